// Round 9
// baseline (5929.177 us; speedup 1.0000x reference)
//
#include <hip/hip_runtime.h>

typedef float f4 __attribute__((ext_vector_type(4)));

#define B_ 32
#define D_ 128
#define T_ 1024
#define K_ 4096
#define NROWS (B_ * T_)   // 32768
#define BM 64             // rows per workgroup; grid 1024 (x2 K-split)
#define LPX 132           // xs row stride (floats): %4==0 for b128 reads

#define SCHED_FENCE() __builtin_amdgcn_sched_barrier(0)

struct MI { float m; int i; };

// numpy computes t = a*a elementwise, THEN pairwise-sums (no fma fusion).
__device__ __forceinline__ float opaquef(float x) { asm volatile("" : "+v"(x)); return x; }

// numpy pairwise_sum base case for n=128: 8 accumulators,
// ((r0+r1)+(r2+r3))+((r4+r5)+(r6+r7)). Bit-exact replica.
__device__ float np_sumsq128(const float* a) {
  float r[8];
#pragma unroll
  for (int j = 0; j < 8; ++j) r[j] = opaquef(a[j] * a[j]);
#pragma unroll
  for (int i = 8; i < 128; i += 8) {
#pragma unroll
    for (int j = 0; j < 8; ++j) r[j] = r[j] + opaquef(a[i + j] * a[i + j]);
  }
  return ((r[0] + r[1]) + (r[2] + r[3])) + ((r[4] + r[5]) + (r[6] + r[7]));
}

__global__ void wsq_kernel(const float* __restrict__ W, float* __restrict__ wsq) {
  int k = blockIdx.x * blockDim.x + threadIdx.x;
  if (k < K_) wsq[k] = np_sumsq128(W + (size_t)k * D_);
}

// Wtb[(k>>8)][d][k&255] = W[k][d]  — K-blocked transpose, coalesced both sides.
__global__ void transpose_kernel(const float* __restrict__ W, float* __restrict__ Wtb) {
  __shared__ float t[32][33];
  int k0 = blockIdx.x * 32, d0 = blockIdx.y * 32;
  int lx = threadIdx.x & 31, ly = threadIdx.x >> 5;  // 256 thr: ly 0..7
  for (int i = ly; i < 32; i += 8) t[i][lx] = W[(size_t)(k0 + i) * D_ + d0 + lx];
  __syncthreads();
  size_t base = (size_t)(k0 >> 8) * (D_ * 256) + (k0 & 255);
  for (int i = ly; i < 32; i += 8) Wtb[base + (size_t)(d0 + i) * 256 + lx] = t[lx][i];
}

// One d2-block: 8 rows x 8 codes x 2 d's = 128 FMAs. W0/W1 = d (codes j0..3 /
// j4..7), W2/W3 = d+1. SEL picks x elements {0,1} or {2,3} of the f4.
// Chain order per acc: strictly ascending d — bit-exact vs OpenBLAS sgemm.
#define FMA_D2(W0, W1, W2, W3, XV, SEL)              \
  do {                                               \
    _Pragma("unroll")                                \
    for (int i_ = 0; i_ < 8; ++i_) {                 \
      float xlo = XV[i_][2 * (SEL)];                 \
      float xhi = XV[i_][2 * (SEL) + 1];             \
      _Pragma("unroll")                              \
      for (int j_ = 0; j_ < 4; ++j_) {               \
        float s_ = acc[i_][j_];                      \
        s_ = __fmaf_rn(xlo, W0[j_], s_);             \
        s_ = __fmaf_rn(xhi, W2[j_], s_);             \
        acc[i_][j_] = s_;                            \
      }                                              \
      _Pragma("unroll")                              \
      for (int j_ = 0; j_ < 4; ++j_) {               \
        float s_ = acc[i_][j_ + 4];                  \
        s_ = __fmaf_rn(xlo, W1[j_], s_);             \
        s_ = __fmaf_rn(xhi, W3[j_], s_);             \
        acc[i_][j_ + 4] = s_;                        \
      }                                              \
    }                                                \
  } while (0)

#define LDW(R0, R1, R2, R3)                          \
  R0 = *(const f4*)(pwb);                            \
  R1 = *(const f4*)(pwb + 16);                       \
  R2 = *(const f4*)(pwb + 1024);                     \
  R3 = *(const f4*)(pwb + 1040);                     \
  pwb += 2048;

__global__ __launch_bounds__(256, 4) void argmin_kernel(
    const float* __restrict__ x, const float* __restrict__ Wtb,
    const float* __restrict__ wsq, MI* __restrict__ partial) {
  __shared__ float xs[BM][LPX];
  __shared__ float xsqs[BM];
  const int tid = threadIdx.x;
  const int blk = blockIdx.x >> 1;    // row-tile id (512 of them)
  const int kh  = blockIdx.x & 1;     // K half: k-tiles kh*8 .. kh*8+7
  const int b  = blk >> 4;            // / (T_/BM)
  const int t0 = (blk & 15) * BM;
  const int tx = tid & 31;            // 8 consecutive codes per 256-tile
  const int ty = tid >> 5;            // rows ty*8 .. ty*8+7

  // stage x tile: xs[tt][d] = x[b, d, t0+tt]   (coalesced along t)
  {
    int tt = tid & 63;
    int d0 = (tid >> 6) * 32;
    for (int dd = 0; dd < 32; ++dd) {
      int d = d0 + dd;
      xs[tt][d] = x[((size_t)b * D_ + d) * T_ + t0 + tt];
    }
  }
  __syncthreads();
  if (tid < BM) xsqs[tid] = np_sumsq128(&xs[tid][0]);
  __syncthreads();

  float xq[8];
#pragma unroll
  for (int i = 0; i < 8; ++i) xq[i] = xsqs[ty * 8 + i];

  float m1[8];
  int   i1[8];
#pragma unroll
  for (int i = 0; i < 8; ++i) { m1[i] = 3.4e38f; i1[i] = 0x7fffffff; }

  for (int kt = kh * 8; kt < kh * 8 + 8; ++kt) {
    const char* pwb = (const char*)Wtb + (size_t)kt * (D_ * 256 * 4) + tx * 32;

    float acc[8][8];
#pragma unroll
    for (int i = 0; i < 8; ++i)
#pragma unroll
      for (int j = 0; j < 8; ++j) acc[i][j] = 0.f;

    // 4-buffer rotation, fence-pinned (r7-proven codegen: 128 VGPR, 76% busy)
    f4 a0, a1, a2, a3, b0, b1, b2, b3, c0, c1, c2, c3, e0, e1, e2, e3;
    LDW(a0, a1, a2, a3)   // d0,d1
    LDW(b0, b1, b2, b3)   // d2,d3
    LDW(c0, c1, c2, c3)   // d4,d5

    for (int s = 0; s < 16; ++s) {
      const int d = s * 8;
      f4 xv[8];
#pragma unroll
      for (int i = 0; i < 8; ++i) xv[i] = *(const f4*)&xs[ty * 8 + i][d];
      LDW(e0, e1, e2, e3)                 // load d+6 (used 3 blocks later)
      SCHED_FENCE();
      FMA_D2(a0, a1, a2, a3, xv, 0);      // d, d+1
      SCHED_FENCE();
      LDW(a0, a1, a2, a3)                 // load d+8
      SCHED_FENCE();
      FMA_D2(b0, b1, b2, b3, xv, 1);      // d+2, d+3
      SCHED_FENCE();
      f4 xw[8];
#pragma unroll
      for (int i = 0; i < 8; ++i) xw[i] = *(const f4*)&xs[ty * 8 + i][d + 4];
      LDW(b0, b1, b2, b3)                 // load d+10
      SCHED_FENCE();
      FMA_D2(c0, c1, c2, c3, xw, 0);      // d+4, d+5
      SCHED_FENCE();
      LDW(c0, c1, c2, c3)                 // load d+12 (last iter: slack overread)
      SCHED_FENCE();
      FMA_D2(e0, e1, e2, e3, xw, 1);      // d+6, d+7
      SCHED_FENCE();
    }

    // epilogue: ascending k within thread (j ascending)
    const int kb = kt * 256 + tx * 8;
    f4 wqa = *(const f4*)&wsq[kb];
    f4 wqb = *(const f4*)&wsq[kb + 4];
#pragma unroll
    for (int j = 0; j < 4; ++j) {
#pragma unroll
      for (int i = 0; i < 8; ++i) {
        float t = __fmaf_rn(-2.0f, acc[i][j], wqa[j]);  // RN(wq - 2*mm)
        float v = __fadd_rn(t, xq[i]);                   // quantizing add
        if (v < m1[i]) { m1[i] = v; i1[i] = kb + j; }    // strict < => first occ.
      }
    }
#pragma unroll
    for (int j = 0; j < 4; ++j) {
#pragma unroll
      for (int i = 0; i < 8; ++i) {
        float t = __fmaf_rn(-2.0f, acc[i][j + 4], wqb[j]);
        float v = __fadd_rn(t, xq[i]);
        if (v < m1[i]) { m1[i] = v; i1[i] = kb + 4 + j; }
      }
    }
  }

  // cross-lane reduce over tx (masks <32 stay within the 32-lane half-wave)
#pragma unroll
  for (int i = 0; i < 8; ++i) {
    float m = m1[i];
    int   idx = i1[i];
#pragma unroll
    for (int mask = 16; mask >= 1; mask >>= 1) {
      float mo = __shfl_xor(m, mask);
      int   io = __shfl_xor(idx, mask);
      if (mo < m || (mo == m && io < idx)) { m = mo; idx = io; }
    }
    if (tx == 0) {
      int rg = b * T_ + t0 + ty * 8 + i;
      MI t; t.m = m; t.i = idx;
      partial[rg * 2 + kh] = t;
    }
  }
}

// merge the two K-halves: lexicographic (value, index) == np first-occurrence
// (half-0 indexes are all < half-1 indexes, so tie keeps half-0).
__global__ void merge_kernel(const MI* __restrict__ partial,
                             int* __restrict__ qout, float* __restrict__ out2) {
  int rg = blockIdx.x * 256 + threadIdx.x;
  MI A = partial[rg * 2];
  MI B = partial[rg * 2 + 1];
  int best = (B.m < A.m) ? B.i : A.i;
  qout[rg] = best;
  out2[rg] = (float)best;
}

// out0[r, d] = W[q[r], d]  — coalesced along d
__global__ void scatter0_kernel(const float* __restrict__ W,
                                const int* __restrict__ q,
                                float* __restrict__ out0) {
  int r = blockIdx.x * 2 + (threadIdx.x >> 7);
  int d = threadIdx.x & 127;
  out0[(size_t)r * D_ + d] = W[(size_t)q[r] * D_ + d];
}

// out1[b, d, t] = W[q[b,t], d]  — coalesced along t
__global__ void scatter1_kernel(const float* __restrict__ W,
                                const int* __restrict__ q,
                                float* __restrict__ out1) {
  int b = blockIdx.x >> 7;
  int d = blockIdx.x & 127;
  for (int t = threadIdx.x; t < T_; t += 256) {
    int k = q[b * T_ + t];
    out1[((size_t)b * D_ + d) * T_ + t] = W[(size_t)k * D_ + d];
  }
}

extern "C" void kernel_launch(void* const* d_in, const int* in_sizes, int n_in,
                              void* d_out, int out_size, void* d_ws, size_t ws_size,
                              hipStream_t stream) {
  const float* x = (const float*)d_in[0];
  const float* W = (const float*)d_in[1];
  float* out  = (float*)d_out;
  float* out0 = out;                           // [B,T,D]  4194304
  float* out1 = out + (size_t)NROWS * D_;      // [B,D,T]  4194304
  float* out2 = out + 2 * (size_t)NROWS * D_;  // [B,T]    32768 (as float)

  float* wsq = (float*)d_ws;                                    // 16 KB
  int*   q   = (int*)((char*)d_ws + K_ * sizeof(float));        // 128 KB
  MI* partial = (MI*)((char*)d_ws + K_ * sizeof(float) + NROWS * sizeof(int));  // 512 KB
  size_t base = K_ * sizeof(float) + NROWS * sizeof(int) + NROWS * 2 * sizeof(MI);
  // Wtb (2 MB + 8 KB prefetch slack): workspace if it fits, else stash in out0
  // (argmin reads it, scatter0 overwrites it afterwards — stream-ordered).
  float* Wtb = (ws_size >= base + (size_t)K_ * D_ * sizeof(float) + 8192)
                   ? (float*)((char*)d_ws + base)
                   : out0;

  wsq_kernel<<<K_ / 256, 256, 0, stream>>>(W, wsq);
  {
    dim3 g(K_ / 32, D_ / 32);
    transpose_kernel<<<g, 256, 0, stream>>>(W, Wtb);
  }
  argmin_kernel<<<2 * NROWS / BM, 256, 0, stream>>>(x, Wtb, wsq, partial);
  merge_kernel<<<NROWS / 256, 256, 0, stream>>>(partial, q, out2);
  scatter0_kernel<<<NROWS / 2, 256, 0, stream>>>(W, q, out0);
  scatter1_kernel<<<B_ * D_, 256, 0, stream>>>(W, q, out1);
}

// Round 10
// 486.971 us; speedup vs baseline: 12.1756x; 12.1756x over previous
//
#include <hip/hip_runtime.h>

typedef float f4 __attribute__((ext_vector_type(4)));

#define B_ 32
#define D_ 128
#define T_ 1024
#define K_ 4096
#define NROWS (B_ * T_)   // 32768
#define BM 64             // rows per workgroup; grid 1024 (x2 K-split)
#define LPX 132           // xs row stride (floats): %4==0 for b128 reads

#define SCHED_FENCE() __builtin_amdgcn_sched_barrier(0)

struct MI { float m; int i; };

// numpy computes t = a*a elementwise, THEN pairwise-sums (no fma fusion).
__device__ __forceinline__ float opaquef(float x) { asm volatile("" : "+v"(x)); return x; }

// numpy pairwise_sum base case for n=128: 8 accumulators,
// ((r0+r1)+(r2+r3))+((r4+r5)+(r6+r7)). Bit-exact replica.
__device__ float np_sumsq128(const float* a) {
  float r[8];
#pragma unroll
  for (int j = 0; j < 8; ++j) r[j] = opaquef(a[j] * a[j]);
#pragma unroll
  for (int i = 8; i < 128; i += 8) {
#pragma unroll
    for (int j = 0; j < 8; ++j) r[j] = r[j] + opaquef(a[i + j] * a[i + j]);
  }
  return ((r[0] + r[1]) + (r[2] + r[3])) + ((r[4] + r[5]) + (r[6] + r[7]));
}

__global__ void wsq_kernel(const float* __restrict__ W, float* __restrict__ wsq) {
  int k = blockIdx.x * blockDim.x + threadIdx.x;
  if (k < K_) wsq[k] = np_sumsq128(W + (size_t)k * D_);
}

// Wtb[(k>>8)][d][k&255] = W[k][d]  — K-blocked transpose, coalesced both sides.
__global__ void transpose_kernel(const float* __restrict__ W, float* __restrict__ Wtb) {
  __shared__ float t[32][33];
  int k0 = blockIdx.x * 32, d0 = blockIdx.y * 32;
  int lx = threadIdx.x & 31, ly = threadIdx.x >> 5;  // 256 thr: ly 0..7
  for (int i = ly; i < 32; i += 8) t[i][lx] = W[(size_t)(k0 + i) * D_ + d0 + lx];
  __syncthreads();
  size_t base = (size_t)(k0 >> 8) * (D_ * 256) + (k0 & 255);
  for (int i = ly; i < 32; i += 8) Wtb[base + (size_t)(d0 + i) * 256 + lx] = t[lx][i];
}

// One d2-block: 8 rows x 8 codes x 2 d's = 128 FMAs. W0/W1 = d (codes j0..3 /
// j4..7), W2/W3 = d+1. SEL picks x elements {0,1} or {2,3} of the f4.
// Chain order per acc: strictly ascending d — bit-exact vs OpenBLAS sgemm.
#define FMA_D2(W0, W1, W2, W3, XV, SEL)              \
  do {                                               \
    _Pragma("unroll")                                \
    for (int i_ = 0; i_ < 8; ++i_) {                 \
      float xlo = XV[i_][2 * (SEL)];                 \
      float xhi = XV[i_][2 * (SEL) + 1];             \
      _Pragma("unroll")                              \
      for (int j_ = 0; j_ < 4; ++j_) {               \
        float s_ = acc[i_][j_];                      \
        s_ = __fmaf_rn(xlo, W0[j_], s_);             \
        s_ = __fmaf_rn(xhi, W2[j_], s_);             \
        acc[i_][j_] = s_;                            \
      }                                              \
      _Pragma("unroll")                              \
      for (int j_ = 0; j_ < 4; ++j_) {               \
        float s_ = acc[i_][j_ + 4];                  \
        s_ = __fmaf_rn(xlo, W1[j_], s_);             \
        s_ = __fmaf_rn(xhi, W3[j_], s_);             \
        acc[i_][j_ + 4] = s_;                        \
      }                                              \
    }                                                \
  } while (0)

#define LDW(R0, R1, R2, R3)                          \
  R0 = *(const f4*)(pwb);                            \
  R1 = *(const f4*)(pwb + 16);                       \
  R2 = *(const f4*)(pwb + 1024);                     \
  R3 = *(const f4*)(pwb + 1040);                     \
  pwb += 2048;

// NOTE launch_bounds (256,2): empirically (r7 vs r8/r9) min-waves arg=4 cuts
// the compiler's VGPR budget to 64 and spills this ~128-reg body to scratch.
// arg=2 compiles to exactly 128 VGPR; HW still allows 4 blocks/CU at 128.
__global__ __launch_bounds__(256, 2) void argmin_kernel(
    const float* __restrict__ x, const float* __restrict__ Wtb,
    const float* __restrict__ wsq, MI* __restrict__ partial) {
  __shared__ float xs[BM][LPX];
  __shared__ float xsqs[BM];
  const int tid = threadIdx.x;
  const int blk = blockIdx.x >> 1;    // row-tile id (512 of them)
  const int kh  = blockIdx.x & 1;     // K half: k-tiles kh*8 .. kh*8+7
  const int b  = blk >> 4;            // / (T_/BM)
  const int t0 = (blk & 15) * BM;
  const int tx = tid & 31;            // 8 consecutive codes per 256-tile
  const int ty = tid >> 5;            // rows ty*8 .. ty*8+7

  // stage x tile: xs[tt][d] = x[b, d, t0+tt]   (coalesced along t)
  {
    int tt = tid & 63;
    int d0 = (tid >> 6) * 32;
    for (int dd = 0; dd < 32; ++dd) {
      int d = d0 + dd;
      xs[tt][d] = x[((size_t)b * D_ + d) * T_ + t0 + tt];
    }
  }
  __syncthreads();
  if (tid < BM) xsqs[tid] = np_sumsq128(&xs[tid][0]);
  __syncthreads();

  float xq[8];
#pragma unroll
  for (int i = 0; i < 8; ++i) xq[i] = xsqs[ty * 8 + i];

  float m1[8];
  int   i1[8];
#pragma unroll
  for (int i = 0; i < 8; ++i) { m1[i] = 3.4e38f; i1[i] = 0x7fffffff; }

  for (int kt = kh * 8; kt < kh * 8 + 8; ++kt) {
    const char* pwb = (const char*)Wtb + (size_t)kt * (D_ * 256 * 4) + tx * 32;

    float acc[8][8];
#pragma unroll
    for (int i = 0; i < 8; ++i)
#pragma unroll
      for (int j = 0; j < 8; ++j) acc[i][j] = 0.f;

    // 4-buffer rotation, fence-pinned (r7-proven codegen: 128 VGPR, 76% busy)
    f4 a0, a1, a2, a3, b0, b1, b2, b3, c0, c1, c2, c3, e0, e1, e2, e3;
    LDW(a0, a1, a2, a3)   // d0,d1
    LDW(b0, b1, b2, b3)   // d2,d3
    LDW(c0, c1, c2, c3)   // d4,d5

    for (int s = 0; s < 16; ++s) {
      const int d = s * 8;
      f4 xv[8];
#pragma unroll
      for (int i = 0; i < 8; ++i) xv[i] = *(const f4*)&xs[ty * 8 + i][d];
      LDW(e0, e1, e2, e3)                 // load d+6 (used 3 blocks later)
      SCHED_FENCE();
      FMA_D2(a0, a1, a2, a3, xv, 0);      // d, d+1
      SCHED_FENCE();
      LDW(a0, a1, a2, a3)                 // load d+8
      SCHED_FENCE();
      FMA_D2(b0, b1, b2, b3, xv, 1);      // d+2, d+3
      SCHED_FENCE();
      f4 xw[8];
#pragma unroll
      for (int i = 0; i < 8; ++i) xw[i] = *(const f4*)&xs[ty * 8 + i][d + 4];
      LDW(b0, b1, b2, b3)                 // load d+10
      SCHED_FENCE();
      FMA_D2(c0, c1, c2, c3, xw, 0);      // d+4, d+5
      SCHED_FENCE();
      LDW(c0, c1, c2, c3)                 // load d+12 (last iter: slack overread)
      SCHED_FENCE();
      FMA_D2(e0, e1, e2, e3, xw, 1);      // d+6, d+7
      SCHED_FENCE();
    }

    // epilogue: ascending k within thread (j ascending)
    const int kb = kt * 256 + tx * 8;
    f4 wqa = *(const f4*)&wsq[kb];
    f4 wqb = *(const f4*)&wsq[kb + 4];
#pragma unroll
    for (int j = 0; j < 4; ++j) {
#pragma unroll
      for (int i = 0; i < 8; ++i) {
        float t = __fmaf_rn(-2.0f, acc[i][j], wqa[j]);  // RN(wq - 2*mm)
        float v = __fadd_rn(t, xq[i]);                   // quantizing add
        if (v < m1[i]) { m1[i] = v; i1[i] = kb + j; }    // strict < => first occ.
      }
    }
#pragma unroll
    for (int j = 0; j < 4; ++j) {
#pragma unroll
      for (int i = 0; i < 8; ++i) {
        float t = __fmaf_rn(-2.0f, acc[i][j + 4], wqb[j]);
        float v = __fadd_rn(t, xq[i]);
        if (v < m1[i]) { m1[i] = v; i1[i] = kb + 4 + j; }
      }
    }
  }

  // cross-lane reduce over tx (masks <32 stay within the 32-lane half-wave)
#pragma unroll
  for (int i = 0; i < 8; ++i) {
    float m = m1[i];
    int   idx = i1[i];
#pragma unroll
    for (int mask = 16; mask >= 1; mask >>= 1) {
      float mo = __shfl_xor(m, mask);
      int   io = __shfl_xor(idx, mask);
      if (mo < m || (mo == m && io < idx)) { m = mo; idx = io; }
    }
    if (tx == 0) {
      int rg = b * T_ + t0 + ty * 8 + i;
      MI t; t.m = m; t.i = idx;
      partial[rg * 2 + kh] = t;
    }
  }
}

// merge the two K-halves: lexicographic (value, index) == np first-occurrence
// (half-0 indexes are all < half-1 indexes, so tie keeps half-0).
__global__ void merge_kernel(const MI* __restrict__ partial,
                             int* __restrict__ qout, float* __restrict__ out2) {
  int rg = blockIdx.x * 256 + threadIdx.x;
  MI A = partial[rg * 2];
  MI B = partial[rg * 2 + 1];
  int best = (B.m < A.m) ? B.i : A.i;
  qout[rg] = best;
  out2[rg] = (float)best;
}

// out0[r, d] = W[q[r], d]  — coalesced along d
__global__ void scatter0_kernel(const float* __restrict__ W,
                                const int* __restrict__ q,
                                float* __restrict__ out0) {
  int r = blockIdx.x * 2 + (threadIdx.x >> 7);
  int d = threadIdx.x & 127;
  out0[(size_t)r * D_ + d] = W[(size_t)q[r] * D_ + d];
}

// out1[b, d, t] = W[q[b,t], d]  — coalesced along t
__global__ void scatter1_kernel(const float* __restrict__ W,
                                const int* __restrict__ q,
                                float* __restrict__ out1) {
  int b = blockIdx.x >> 7;
  int d = blockIdx.x & 127;
  for (int t = threadIdx.x; t < T_; t += 256) {
    int k = q[b * T_ + t];
    out1[((size_t)b * D_ + d) * T_ + t] = W[(size_t)k * D_ + d];
  }
}

extern "C" void kernel_launch(void* const* d_in, const int* in_sizes, int n_in,
                              void* d_out, int out_size, void* d_ws, size_t ws_size,
                              hipStream_t stream) {
  const float* x = (const float*)d_in[0];
  const float* W = (const float*)d_in[1];
  float* out  = (float*)d_out;
  float* out0 = out;                           // [B,T,D]  4194304
  float* out1 = out + (size_t)NROWS * D_;      // [B,D,T]  4194304
  float* out2 = out + 2 * (size_t)NROWS * D_;  // [B,T]    32768 (as float)

  float* wsq = (float*)d_ws;                                    // 16 KB
  int*   q   = (int*)((char*)d_ws + K_ * sizeof(float));        // 128 KB
  MI* partial = (MI*)((char*)d_ws + K_ * sizeof(float) + NROWS * sizeof(int));  // 512 KB
  size_t base = K_ * sizeof(float) + NROWS * sizeof(int) + NROWS * 2 * sizeof(MI);
  // Wtb (2 MB + 8 KB prefetch slack): workspace if it fits, else stash in out0
  // (argmin reads it, scatter0 overwrites it afterwards — stream-ordered).
  float* Wtb = (ws_size >= base + (size_t)K_ * D_ * sizeof(float) + 8192)
                   ? (float*)((char*)d_ws + base)
                   : out0;

  wsq_kernel<<<K_ / 256, 256, 0, stream>>>(W, wsq);
  {
    dim3 g(K_ / 32, D_ / 32);
    transpose_kernel<<<g, 256, 0, stream>>>(W, Wtb);
  }
  argmin_kernel<<<2 * NROWS / BM, 256, 0, stream>>>(x, Wtb, wsq, partial);
  merge_kernel<<<NROWS / 256, 256, 0, stream>>>(partial, q, out2);
  scatter0_kernel<<<NROWS / 2, 256, 0, stream>>>(W, q, out0);
  scatter1_kernel<<<B_ * D_, 256, 0, stream>>>(W, q, out1);
}

// Round 11
// 398.138 us; speedup vs baseline: 14.8923x; 1.2231x over previous
//
#include <hip/hip_runtime.h>

typedef float  f4     __attribute__((ext_vector_type(4)));
typedef short  short8 __attribute__((ext_vector_type(8)));

#define B_ 32
#define D_ 128
#define T_ 1024
#define K_ 4096
#define NROWS (B_ * T_)   // 32768
#define LPX 132
#define INF_ 3.4e38f

// numpy computes t = a*a elementwise, THEN pairwise-sums (no fma fusion).
__device__ __forceinline__ float opaquef(float x) { asm volatile("" : "+v"(x)); return x; }

// numpy pairwise_sum base case for n=128: 8 accumulators,
// ((r0+r1)+(r2+r3))+((r4+r5)+(r6+r7)). Bit-exact replica.
__device__ float np_sumsq128(const float* a) {
  float r[8];
#pragma unroll
  for (int j = 0; j < 8; ++j) r[j] = opaquef(a[j] * a[j]);
#pragma unroll
  for (int i = 8; i < 128; i += 8) {
#pragma unroll
    for (int j = 0; j < 8; ++j) r[j] = r[j] + opaquef(a[i + j] * a[i + j]);
  }
  return ((r[0] + r[1]) + (r[2] + r[3])) + ((r[4] + r[5]) + (r[6] + r[7]));
}

// round-to-nearest-even fp32 -> bf16 (deterministic, rel err <= 2^-9)
__device__ __forceinline__ short bf16_rne(float f) {
  unsigned u = __float_as_uint(f);
  unsigned r = (u + 0x7FFFu + ((u >> 16) & 1u)) >> 16;
  return (short)r;
}

__global__ void wsq_kernel(const float* __restrict__ W, float* __restrict__ wsq,
                           unsigned* __restrict__ maxwsq) {
  int k = blockIdx.x * blockDim.x + threadIdx.x;
  if (k < K_) {
    float s = np_sumsq128(W + (size_t)k * D_);
    wsq[k] = s;
    atomicMax(maxwsq, __float_as_uint(s));  // positive floats: uint order == float order
  }
}

// Wbf fragment layout for mfma_f32_16x16x32_bf16 B-operand:
// elem e = ((ct*4+kk)*64 + lane)*8 + j  holds bf16(W[ct*16 + (lane&15)][kk*32 + ((lane>>4)&3)*8 + j])
__global__ void wbf_prep_kernel(const float* __restrict__ W, short* __restrict__ Wbf) {
  int e = blockIdx.x * 256 + threadIdx.x;   // 524288 total
  int j = e & 7, lane = (e >> 3) & 63, kk = (e >> 9) & 3, ct = e >> 11;
  int code = (ct << 4) + (lane & 15);
  int k = (kk << 5) + (((lane >> 4) & 3) << 3) + j;
  Wbf[e] = bf16_rne(W[(size_t)code * D_ + k]);
}

// Two-phase MFMA filter: phase 0 per-row min of u = wsq - 2*x.w (bf16 filter),
// phase 1 collects all codes with u <= min + WIN into per-row candidate lists.
// WIN is a rigorous bound covering bf16 quantization + accumulation-order +
// the final +xsq rounding bin, so the np.argmin winner is always a candidate.
__global__ __launch_bounds__(256) void filter_kernel(
    const float* __restrict__ x, const short* __restrict__ Wbf,
    const float* __restrict__ wsq, const unsigned* __restrict__ maxwsq,
    float* __restrict__ xsq_g, int* __restrict__ cnt, int* __restrict__ cand) {
  __shared__ float xs[64][LPX];
  __shared__ float xsqs[64];
  const int tid = threadIdx.x;
  const int blkrow = blockIdx.x * 64;
  const int b = blockIdx.x >> 4, t0 = (blockIdx.x & 15) << 6;

  {  // stage x rows (coalesced along t)
    int tt = tid & 63, d0 = (tid >> 6) * 32;
    for (int dd = 0; dd < 32; ++dd) {
      int d = d0 + dd;
      xs[tt][d] = x[((size_t)b * D_ + d) * T_ + t0 + tt];
    }
  }
  __syncthreads();
  if (tid < 64) {
    float s = np_sumsq128(&xs[tid][0]);
    xsqs[tid] = s;
    xsq_g[blkrow + tid] = s;
  }
  __syncthreads();

  const int w = tid >> 6, lane = tid & 63;
  const int lrow = w * 16;

  // A fragment: lane holds rows lrow+(lane&15), k = kk*32 + ((lane>>4)&3)*8 + j
  short8 afr[4];
#pragma unroll
  for (int kk = 0; kk < 4; ++kk)
#pragma unroll
    for (int j = 0; j < 8; ++j)
      afr[kk][j] = bf16_rne(xs[lrow + (lane & 15)][(kk << 5) + (((lane >> 4) & 3) << 3) + j]);

  const float mw = sqrtf(__uint_as_float(*maxwsq)) * 1.0001f;

  float umin[4] = {INF_, INF_, INF_, INF_};
  float lim[4];
  for (int phase = 0; phase < 2; ++phase) {
    for (int ct = 0; ct < 256; ++ct) {
      short8 bfr[4];
#pragma unroll
      for (int kk = 0; kk < 4; ++kk)
        bfr[kk] = ((const short8*)Wbf)[(((ct << 2) + kk) << 6) + lane];
      f4 acc = {0.f, 0.f, 0.f, 0.f};
#pragma unroll
      for (int kk = 0; kk < 4; ++kk)
        acc = __builtin_amdgcn_mfma_f32_16x16x32_bf16(afr[kk], bfr[kk], acc, 0, 0, 0);
      float wq = wsq[(ct << 4) + (lane & 15)];
      if (phase == 0) {
#pragma unroll
        for (int j = 0; j < 4; ++j)
          umin[j] = fminf(umin[j], __fmaf_rn(-2.f, acc[j], wq));
      } else {
#pragma unroll
        for (int j = 0; j < 4; ++j) {
          float u = __fmaf_rn(-2.f, acc[j], wq);
          if (u <= lim[j]) {
            int row = blkrow + lrow + (((lane >> 4) & 3) << 2) + j;  // C: row=(lane>>4)*4+reg
            int pos = atomicAdd(&cnt[row], 1);
            if (pos < 16) cand[(row << 4) + pos] = (ct << 4) + (lane & 15);  // C: col=lane&15
          }
        }
      }
    }
    if (phase == 0) {
      // reduce mins over the 16 code-lanes sharing the same rows
#pragma unroll
      for (int j = 0; j < 4; ++j) {
#pragma unroll
        for (int mask = 1; mask < 16; mask <<= 1)
          umin[j] = fminf(umin[j], __shfl_xor(umin[j], mask));
        int rl = (((lane >> 4) & 3) << 2) + j;
        float xn = sqrtf(xsqs[lrow + rl]) * 1.0001f;
        // WIN = 4*E_mm + (+xsq rounding bin) + slack; E_mm = bf16-quant + accum-order
        lim[j] = umin[j] + 4.f * (0.0079f * xn * mw + 1e-5f) + 2.6e-5f;
      }
    }
  }
}

// Exact rescore: lane c replays the bit-exact np fp32 pipeline for candidate c;
// lexicographic (v, k) min == np.argmin first-occurrence.
__global__ __launch_bounds__(256) void rescore_kernel(
    const float* __restrict__ x, const float* __restrict__ W,
    const float* __restrict__ wsq, const float* __restrict__ xsq,
    const int* __restrict__ cnt, const int* __restrict__ cand,
    int* __restrict__ qout, float* __restrict__ out2) {
  const int wid = threadIdx.x >> 6, lane = threadIdx.x & 63;
  const int r = blockIdx.x * 4 + wid;
  int c = cnt[r]; if (c > 16) c = 16;
  int best;
  if (c == 1) {
    best = cand[r << 4];
  } else {
    float v = INF_; int k = 0x7fffffff;
    if (lane < c) {
      k = cand[(r << 4) + lane];
      const float* wr = W + (size_t)k * D_;
      const float* xr = x + ((size_t)(r >> 10) * D_) * T_ + (r & 1023);
      float mm = 0.f;
#pragma unroll 16
      for (int d = 0; d < D_; ++d)
        mm = __fmaf_rn(xr[(size_t)d * T_], wr[d], mm);   // ascending-d sgemm chain
      v = __fadd_rn(__fmaf_rn(-2.f, mm, wsq[k]), xsq[r]);  // RN(wq-2mm) then +xsq
    }
#pragma unroll
    for (int mask = 1; mask < 16; mask <<= 1) {
      float vo = __shfl_xor(v, mask); int ko = __shfl_xor(k, mask);
      if (vo < v || (vo == v && ko < k)) { v = vo; k = ko; }
    }
    best = k;
  }
  if (lane == 0) { qout[r] = best; out2[r] = (float)best; }
}

// out0[r, d] = W[q[r], d]  — coalesced along d
__global__ void scatter0_kernel(const float* __restrict__ W,
                                const int* __restrict__ q,
                                float* __restrict__ out0) {
  int r = blockIdx.x * 2 + (threadIdx.x >> 7);
  int d = threadIdx.x & 127;
  out0[(size_t)r * D_ + d] = W[(size_t)q[r] * D_ + d];
}

// out1[b, d, t] = W[q[b,t], d]  — coalesced along t
__global__ void scatter1_kernel(const float* __restrict__ W,
                                const int* __restrict__ q,
                                float* __restrict__ out1) {
  int b = blockIdx.x >> 7;
  int d = blockIdx.x & 127;
  for (int t = threadIdx.x; t < T_; t += 256) {
    int k = q[b * T_ + t];
    out1[((size_t)b * D_ + d) * T_ + t] = W[(size_t)k * D_ + d];
  }
}

extern "C" void kernel_launch(void* const* d_in, const int* in_sizes, int n_in,
                              void* d_out, int out_size, void* d_ws, size_t ws_size,
                              hipStream_t stream) {
  const float* x = (const float*)d_in[0];
  const float* W = (const float*)d_in[1];
  float* out  = (float*)d_out;
  float* out0 = out;                           // [B,T,D]  4194304
  float* out1 = out + (size_t)NROWS * D_;      // [B,D,T]  4194304
  float* out2 = out + 2 * (size_t)NROWS * D_;  // [B,T]    32768 (as float)

  // small scratch in ws (~404 KB; r9/r10 proved >=656 KB usable)
  float*    wsq  = (float*)d_ws;                               // 16 KB
  float*    xsq  = (float*)((char*)d_ws + (16 << 10));         // 128 KB
  int*      q    = (int*)((char*)d_ws + (144 << 10));          // 128 KB
  int*      cnt  = (int*)((char*)d_ws + (272 << 10));          // 128 KB
  unsigned* maxw = (unsigned*)((char*)d_ws + (400 << 10));     // 4 B

  // big scratch in out0 (read before scatter0 overwrites it; stream-ordered)
  int*   cand = (int*)out0;                          // 32768*16*4 = 2 MB
  short* Wbf  = (short*)((char*)(void*)out0 + (2 << 20));  // 1 MB

  hipMemsetAsync((char*)d_ws + (272 << 10), 0, (128 << 10) + 64, stream);  // cnt + maxw
  wsq_kernel<<<K_ / 256, 256, 0, stream>>>(W, wsq, maxw);
  wbf_prep_kernel<<<K_ * D_ / 256, 256, 0, stream>>>(W, Wbf);
  filter_kernel<<<NROWS / 64, 256, 0, stream>>>(x, Wbf, wsq, maxw, xsq, cnt, cand);
  rescore_kernel<<<NROWS / 4, 256, 0, stream>>>(x, W, wsq, xsq, cnt, cand, q, out2);
  scatter0_kernel<<<NROWS / 2, 256, 0, stream>>>(W, q, out0);
  scatter1_kernel<<<B_ * D_, 256, 0, stream>>>(W, q, out1);
}

// Round 12
// 208.934 us; speedup vs baseline: 28.3783x; 1.9056x over previous
//
#include <hip/hip_runtime.h>

typedef float  f4     __attribute__((ext_vector_type(4)));
typedef short  short8 __attribute__((ext_vector_type(8)));

#define B_ 32
#define D_ 128
#define T_ 1024
#define K_ 4096
#define NROWS (B_ * T_)   // 32768
#define LPX 132
#define INF_ 3.4e38f

#define SCHED_FENCE() __builtin_amdgcn_sched_barrier(0)

// numpy computes t = a*a elementwise, THEN pairwise-sums (no fma fusion).
__device__ __forceinline__ float opaquef(float x) { asm volatile("" : "+v"(x)); return x; }

// numpy pairwise_sum base case for n=128: 8 accumulators,
// ((r0+r1)+(r2+r3))+((r4+r5)+(r6+r7)). Bit-exact replica.
__device__ float np_sumsq128(const float* a) {
  float r[8];
#pragma unroll
  for (int j = 0; j < 8; ++j) r[j] = opaquef(a[j] * a[j]);
#pragma unroll
  for (int i = 8; i < 128; i += 8) {
#pragma unroll
    for (int j = 0; j < 8; ++j) r[j] = r[j] + opaquef(a[i + j] * a[i + j]);
  }
  return ((r[0] + r[1]) + (r[2] + r[3])) + ((r[4] + r[5]) + (r[6] + r[7]));
}

// round-to-nearest-even fp32 -> bf16 (deterministic, rel err <= 2^-9)
__device__ __forceinline__ short bf16_rne(float f) {
  unsigned u = __float_as_uint(f);
  unsigned r = (u + 0x7FFFu + ((u >> 16) & 1u)) >> 16;
  return (short)r;
}

__global__ void wsq_kernel(const float* __restrict__ W, float* __restrict__ wsq,
                           unsigned* __restrict__ maxwsq) {
  int k = blockIdx.x * blockDim.x + threadIdx.x;
  if (k < K_) {
    float s = np_sumsq128(W + (size_t)k * D_);
    wsq[k] = s;
    atomicMax(maxwsq, __float_as_uint(s));  // positive floats: uint order == float order
  }
}

// Wbf fragment layout for mfma_f32_16x16x32_bf16 B-operand:
// elem e = ((ct*4+kk)*64 + lane)*8 + j holds bf16(W[ct*16 + (lane&15)][kk*32 + (lane>>4)*8 + j])
__global__ void wbf_prep_kernel(const float* __restrict__ W, short* __restrict__ Wbf) {
  int e = blockIdx.x * 256 + threadIdx.x;   // 524288 total
  int j = e & 7, lane = (e >> 3) & 63, kk = (e >> 9) & 3, ct = e >> 11;
  int code = (ct << 4) + (lane & 15);
  int k = (kk << 5) + (((lane >> 4) & 3) << 3) + j;
  Wbf[e] = bf16_rne(W[(size_t)code * D_ + k]);
}

#define LDB(R0, R1, R2, R3, WQ, CT)            \
  R0 = bp[((CT) * 4 + 0) * 64 + lane];         \
  R1 = bp[((CT) * 4 + 1) * 64 + lane];         \
  R2 = bp[((CT) * 4 + 2) * 64 + lane];         \
  R3 = bp[((CT) * 4 + 3) * 64 + lane];         \
  WQ = wsq[((CT) << 4) + cidx];

// 2 row-tiles x (2 independent chains of 2 MFMAs) per ct; acc split kk{0,1}+kk{2,3}
// summed after (covered by the accum-order term of WIN).
#define CONSUME(B0, B1, B2, B3, WQ, CT)                                        \
  do {                                                                         \
    f4 z = {0.f, 0.f, 0.f, 0.f};                                               \
    f4 A0 = __builtin_amdgcn_mfma_f32_16x16x32_bf16(afr0[0], B0, z, 0, 0, 0);  \
    A0 = __builtin_amdgcn_mfma_f32_16x16x32_bf16(afr0[1], B1, A0, 0, 0, 0);    \
    f4 A1 = __builtin_amdgcn_mfma_f32_16x16x32_bf16(afr0[2], B2, z, 0, 0, 0);  \
    A1 = __builtin_amdgcn_mfma_f32_16x16x32_bf16(afr0[3], B3, A1, 0, 0, 0);    \
    f4 C0 = __builtin_amdgcn_mfma_f32_16x16x32_bf16(afr1[0], B0, z, 0, 0, 0);  \
    C0 = __builtin_amdgcn_mfma_f32_16x16x32_bf16(afr1[1], B1, C0, 0, 0, 0);    \
    f4 C1 = __builtin_amdgcn_mfma_f32_16x16x32_bf16(afr1[2], B2, z, 0, 0, 0);  \
    C1 = __builtin_amdgcn_mfma_f32_16x16x32_bf16(afr1[3], B3, C1, 0, 0, 0);    \
    if (phase == 0) {                                                          \
      _Pragma("unroll")                                                        \
      for (int j = 0; j < 4; ++j) {                                            \
        umin[0][j] = fminf(umin[0][j], __fmaf_rn(-2.f, A0[j] + A1[j], WQ));    \
        umin[1][j] = fminf(umin[1][j], __fmaf_rn(-2.f, C0[j] + C1[j], WQ));    \
      }                                                                        \
    } else {                                                                   \
      _Pragma("unroll")                                                        \
      for (int j = 0; j < 4; ++j) {                                            \
        float u0 = __fmaf_rn(-2.f, A0[j] + A1[j], WQ);                         \
        if (u0 <= lim[0][j]) {                                                 \
          int row = blkrow + (q << 2) + j;                                     \
          int pos = atomicAdd(&cnt[row], 1);                                   \
          if (pos < 16) cand[(row << 4) + pos] = ((CT) << 4) + cidx;           \
        }                                                                      \
        float u1 = __fmaf_rn(-2.f, C0[j] + C1[j], WQ);                        \
        if (u1 <= lim[1][j]) {                                                 \
          int row = blkrow + 16 + (q << 2) + j;                                \
          int pos = atomicAdd(&cnt[row], 1);                                   \
          if (pos < 16) cand[(row << 4) + pos] = ((CT) << 4) + cidx;           \
        }                                                                      \
      }                                                                        \
    }                                                                          \
  } while (0)

// Two-phase MFMA filter. Block = 32 rows (2 tiles), 4 waves each covering a
// 64-ct quarter of the codebook; phase-0 mins merged across waves in LDS.
// WIN covers bf16 quantization + accumulation-order + the +xsq rounding bin,
// so the np.argmin winner is always a candidate (same formula as r11, passed).
__global__ __launch_bounds__(256) void filter_kernel(
    const float* __restrict__ x, const short* __restrict__ Wbf,
    const float* __restrict__ wsq, const unsigned* __restrict__ maxwsq,
    float* __restrict__ xsq_g, int* __restrict__ cnt, int* __restrict__ cand) {
  __shared__ float xs[32][LPX];
  __shared__ float xsqs[32];
  __shared__ float umin_sh[32][4];
  const int tid = threadIdx.x;
  const int blkrow = blockIdx.x * 32;
  const int b = blockIdx.x >> 5, t0 = (blockIdx.x & 31) << 5;

  {  // stage x rows (coalesced along t)
    int tt = tid & 31, d0 = (tid >> 5) * 16;
    for (int dd = 0; dd < 16; ++dd) {
      int d = d0 + dd;
      xs[tt][d] = x[((size_t)b * D_ + d) * T_ + t0 + tt];
    }
  }
  __syncthreads();
  if (tid < 32) {
    float s = np_sumsq128(&xs[tid][0]);
    xsqs[tid] = s;
    xsq_g[blkrow + tid] = s;
  }
  __syncthreads();

  const int w = tid >> 6, lane = tid & 63;
  const int cidx = lane & 15;         // code within ct tile
  const int q = lane >> 4;            // k-slice / C-row group
  const short8* bp = (const short8*)Wbf;

  // A fragments for both row-tiles: lane holds row t*16+(lane&15), k = kk*32+q*8+j
  short8 afr0[4], afr1[4];
#pragma unroll
  for (int kk = 0; kk < 4; ++kk)
#pragma unroll
    for (int j = 0; j < 8; ++j) {
      int k = (kk << 5) + (q << 3) + j;
      afr0[kk][j] = bf16_rne(xs[cidx][k]);
      afr1[kk][j] = bf16_rne(xs[16 + cidx][k]);
    }

  const float mw = sqrtf(__uint_as_float(*maxwsq)) * 1.0001f;

  float umin[2][4] = {{INF_, INF_, INF_, INF_}, {INF_, INF_, INF_, INF_}};
  float lim[2][4] = {{INF_, INF_, INF_, INF_}, {INF_, INF_, INF_, INF_}};
  const int ct0 = w << 6;             // this wave's 64-ct quarter

  for (int phase = 0; phase < 2; ++phase) {
    short8 p0, p1, p2, p3, n0, n1, n2, n3;
    float wqc, wqn;
    LDB(p0, p1, p2, p3, wqc, ct0)
    for (int s = 0; s < 32; ++s) {
      const int c = ct0 + s * 2;
      LDB(n0, n1, n2, n3, wqn, c + 1)
      SCHED_FENCE();
      CONSUME(p0, p1, p2, p3, wqc, c);
      SCHED_FENCE();
      LDB(p0, p1, p2, p3, wqc, c + 2)   // last iter overreads into safe scratch
      SCHED_FENCE();
      CONSUME(n0, n1, n2, n3, wqn, c + 1);
      SCHED_FENCE();
    }
    if (phase == 0) {
      // min over the 16 code-lanes (butterfly) -> per-row quarter-min
#pragma unroll
      for (int t = 0; t < 2; ++t)
#pragma unroll
        for (int j = 0; j < 4; ++j) {
          float m = umin[t][j];
#pragma unroll
          for (int mask = 1; mask < 16; mask <<= 1)
            m = fminf(m, __shfl_xor(m, mask));
          if (cidx == 0) umin_sh[t * 16 + (q << 2) + j][w] = m;
        }
      __syncthreads();
      // merge quarters + window
#pragma unroll
      for (int t = 0; t < 2; ++t)
#pragma unroll
        for (int j = 0; j < 4; ++j) {
          int rl = t * 16 + (q << 2) + j;
          float m2 = fminf(fminf(umin_sh[rl][0], umin_sh[rl][1]),
                           fminf(umin_sh[rl][2], umin_sh[rl][3]));
          float xn = sqrtf(xsqs[rl]) * 1.0001f;
          lim[t][j] = m2 + 4.f * (0.0079f * xn * mw + 1e-5f) + 2.6e-5f;
        }
    }
  }
}

// Exact rescore: lane c replays the bit-exact np fp32 pipeline for candidate c;
// lexicographic (v, k) min == np.argmin first-occurrence.
__global__ __launch_bounds__(256) void rescore_kernel(
    const float* __restrict__ x, const float* __restrict__ W,
    const float* __restrict__ wsq, const float* __restrict__ xsq,
    const int* __restrict__ cnt, const int* __restrict__ cand,
    int* __restrict__ qout, float* __restrict__ out2) {
  const int wid = threadIdx.x >> 6, lane = threadIdx.x & 63;
  const int r = blockIdx.x * 4 + wid;
  int c = cnt[r]; if (c > 16) c = 16;
  int best;
  if (c == 1) {
    best = cand[r << 4];
  } else {
    float v = INF_; int k = 0x7fffffff;
    if (lane < c) {
      k = cand[(r << 4) + lane];
      const float* wr = W + (size_t)k * D_;
      const float* xr = x + ((size_t)(r >> 10) * D_) * T_ + (r & 1023);
      float mm = 0.f;
#pragma unroll 16
      for (int d = 0; d < D_; ++d)
        mm = __fmaf_rn(xr[(size_t)d * T_], wr[d], mm);   // ascending-d sgemm chain
      v = __fadd_rn(__fmaf_rn(-2.f, mm, wsq[k]), xsq[r]);  // RN(wq-2mm) then +xsq
    }
#pragma unroll
    for (int mask = 1; mask < 16; mask <<= 1) {
      float vo = __shfl_xor(v, mask); int ko = __shfl_xor(k, mask);
      if (vo < v || (vo == v && ko < k)) { v = vo; k = ko; }
    }
    best = k;
  }
  if (lane == 0) { qout[r] = best; out2[r] = (float)best; }
}

// out0[r, d] = W[q[r], d]  — coalesced along d
__global__ void scatter0_kernel(const float* __restrict__ W,
                                const int* __restrict__ q,
                                float* __restrict__ out0) {
  int r = blockIdx.x * 2 + (threadIdx.x >> 7);
  int d = threadIdx.x & 127;
  out0[(size_t)r * D_ + d] = W[(size_t)q[r] * D_ + d];
}

// out1[b, d, t] = W[q[b,t], d]  — coalesced along t
__global__ void scatter1_kernel(const float* __restrict__ W,
                                const int* __restrict__ q,
                                float* __restrict__ out1) {
  int b = blockIdx.x >> 7;
  int d = blockIdx.x & 127;
  for (int t = threadIdx.x; t < T_; t += 256) {
    int k = q[b * T_ + t];
    out1[((size_t)b * D_ + d) * T_ + t] = W[(size_t)k * D_ + d];
  }
}

extern "C" void kernel_launch(void* const* d_in, const int* in_sizes, int n_in,
                              void* d_out, int out_size, void* d_ws, size_t ws_size,
                              hipStream_t stream) {
  const float* x = (const float*)d_in[0];
  const float* W = (const float*)d_in[1];
  float* out  = (float*)d_out;
  float* out0 = out;                           // [B,T,D]  4194304
  float* out1 = out + (size_t)NROWS * D_;      // [B,D,T]  4194304
  float* out2 = out + 2 * (size_t)NROWS * D_;  // [B,T]    32768 (as float)

  // small scratch in ws (~404 KB; r9/r10 proved >=656 KB usable)
  float*    wsq  = (float*)d_ws;                               // 16 KB
  float*    xsq  = (float*)((char*)d_ws + (16 << 10));         // 128 KB
  int*      q    = (int*)((char*)d_ws + (144 << 10));          // 128 KB
  int*      cnt  = (int*)((char*)d_ws + (272 << 10));          // 128 KB
  unsigned* maxw = (unsigned*)((char*)d_ws + (400 << 10));     // 4 B

  // big scratch in out0 (read before scatter0 overwrites it; stream-ordered)
  int*   cand = (int*)out0;                          // 32768*16*4 = 2 MB
  short* Wbf  = (short*)((char*)(void*)out0 + (2 << 20));  // 1 MB

  hipMemsetAsync((char*)d_ws + (272 << 10), 0, (128 << 10) + 64, stream);  // cnt + maxw
  wsq_kernel<<<K_ / 256, 256, 0, stream>>>(W, wsq, maxw);
  wbf_prep_kernel<<<K_ * D_ / 256, 256, 0, stream>>>(W, Wbf);
  filter_kernel<<<NROWS / 32, 256, 0, stream>>>(x, Wbf, wsq, maxw, xsq, cnt, cand);
  rescore_kernel<<<NROWS / 4, 256, 0, stream>>>(x, W, wsq, xsq, cnt, cand, q, out2);
  scatter0_kernel<<<NROWS / 2, 256, 0, stream>>>(W, q, out0);
  scatter1_kernel<<<B_ * D_, 256, 0, stream>>>(W, q, out1);
}

// Round 14
// 208.246 us; speedup vs baseline: 28.4720x; 1.0033x over previous
//
#include <hip/hip_runtime.h>

typedef float  f4     __attribute__((ext_vector_type(4)));
typedef short  short8 __attribute__((ext_vector_type(8)));

#define B_ 32
#define D_ 128
#define T_ 1024
#define K_ 4096
#define NROWS (B_ * T_)   // 32768
#define LPX 132
#define INF_ 3.4e38f

#define SCHED_FENCE() __builtin_amdgcn_sched_barrier(0)

// numpy computes t = a*a elementwise, THEN pairwise-sums (no fma fusion).
__device__ __forceinline__ float opaquef(float x) { asm volatile("" : "+v"(x)); return x; }

// numpy pairwise_sum base case for n=128: 8 accumulators,
// ((r0+r1)+(r2+r3))+((r4+r5)+(r6+r7)). Bit-exact replica (r12-proven).
__device__ float np_sumsq128(const float* a) {
  float r[8];
#pragma unroll
  for (int j = 0; j < 8; ++j) r[j] = opaquef(a[j] * a[j]);
#pragma unroll
  for (int i = 8; i < 128; i += 8) {
#pragma unroll
    for (int j = 0; j < 8; ++j) r[j] = r[j] + opaquef(a[i + j] * a[i + j]);
  }
  return ((r[0] + r[1]) + (r[2] + r[3])) + ((r[4] + r[5]) + (r[6] + r[7]));
}

// round-to-nearest-even fp32 -> bf16 (deterministic, rel err <= 2^-9)
__device__ __forceinline__ short bf16_rne(float f) {
  unsigned u = __float_as_uint(f);
  unsigned r = (u + 0x7FFFu + ((u >> 16) & 1u)) >> 16;
  return (short)r;
}

__global__ void wsq_kernel(const float* __restrict__ W, float* __restrict__ wsq,
                           unsigned* __restrict__ maxwsq) {
  int k = blockIdx.x * blockDim.x + threadIdx.x;
  if (k < K_) {
    float s = np_sumsq128(W + (size_t)k * D_);
    wsq[k] = s;
    atomicMax(maxwsq, __float_as_uint(s));  // positive floats: uint order == float order
  }
}

// Wbf fragment layout for mfma_f32_16x16x32_bf16 B-operand:
// elem e = ((ct*4+kk)*64 + lane)*8 + j holds bf16(W[ct*16 + (lane&15)][kk*32 + (lane>>4)*8 + j])
__global__ void wbf_prep_kernel(const float* __restrict__ W, short* __restrict__ Wbf) {
  int e = blockIdx.x * 256 + threadIdx.x;   // 524288 total
  int j = e & 7, lane = (e >> 3) & 63, kk = (e >> 9) & 3, ct = e >> 11;
  int code = (ct << 4) + (lane & 15);
  int k = (kk << 5) + (((lane >> 4) & 3) << 3) + j;
  Wbf[e] = bf16_rne(W[(size_t)code * D_ + k]);
}

// B-fragment load: linear byte pointer + imm offsets. Byte address
// ct*4096 + kk*1024 + lane*16 — identical addresses to r12's indexed form.
#define LDB(R0, R1, R2, R3, WQ)               \
  R0 = *(const short8*)(pwb);                 \
  R1 = *(const short8*)(pwb + 1024);          \
  R2 = *(const short8*)(pwb + 2048);          \
  R3 = *(const short8*)(pwb + 3072);          \
  WQ = *pwq;                                  \
  pwb += 4096; pwq += 16;

// 2 row-tiles x (2 independent chains of 2 MFMAs) per ct; acc split kk{0,1}+kk{2,3}
// summed after (covered by the accum-order term of WIN). IDENTICAL to r12.
#define CONSUME(B0, B1, B2, B3, WQ, CT)                                        \
  do {                                                                         \
    f4 z = {0.f, 0.f, 0.f, 0.f};                                               \
    f4 A0 = __builtin_amdgcn_mfma_f32_16x16x32_bf16(afr0[0], B0, z, 0, 0, 0);  \
    A0 = __builtin_amdgcn_mfma_f32_16x16x32_bf16(afr0[1], B1, A0, 0, 0, 0);    \
    f4 A1 = __builtin_amdgcn_mfma_f32_16x16x32_bf16(afr0[2], B2, z, 0, 0, 0);  \
    A1 = __builtin_amdgcn_mfma_f32_16x16x32_bf16(afr0[3], B3, A1, 0, 0, 0);    \
    f4 C0 = __builtin_amdgcn_mfma_f32_16x16x32_bf16(afr1[0], B0, z, 0, 0, 0);  \
    C0 = __builtin_amdgcn_mfma_f32_16x16x32_bf16(afr1[1], B1, C0, 0, 0, 0);    \
    f4 C1 = __builtin_amdgcn_mfma_f32_16x16x32_bf16(afr1[2], B2, z, 0, 0, 0);  \
    C1 = __builtin_amdgcn_mfma_f32_16x16x32_bf16(afr1[3], B3, C1, 0, 0, 0);    \
    if (phase == 0) {                                                          \
      _Pragma("unroll")                                                        \
      for (int j = 0; j < 4; ++j) {                                            \
        umin[0][j] = fminf(umin[0][j], __fmaf_rn(-2.f, A0[j] + A1[j], WQ));    \
        umin[1][j] = fminf(umin[1][j], __fmaf_rn(-2.f, C0[j] + C1[j], WQ));    \
      }                                                                        \
    } else {                                                                   \
      _Pragma("unroll")                                                        \
      for (int j = 0; j < 4; ++j) {                                            \
        float u0 = __fmaf_rn(-2.f, A0[j] + A1[j], WQ);                         \
        if (u0 <= lim[0][j]) {                                                 \
          int row = blkrow + (q << 2) + j;                                     \
          int pos = atomicAdd(&cnt[row], 1);                                   \
          if (pos < 16) cand[(row << 4) + pos] = ((CT) << 4) + cidx;           \
        }                                                                      \
        float u1 = __fmaf_rn(-2.f, C0[j] + C1[j], WQ);                        \
        if (u1 <= lim[1][j]) {                                                 \
          int row = blkrow + 16 + (q << 2) + j;                                \
          int pos = atomicAdd(&cnt[row], 1);                                   \
          if (pos < 16) cand[(row << 4) + pos] = ((CT) << 4) + cidx;           \
        }                                                                      \
      }                                                                        \
    }                                                                          \
  } while (0)

// Two-phase MFMA filter. Block = 32 rows (2 tiles), 4 waves each covering a
// 64-ct quarter; r12's 2-buffer ping-pong prefetch (proven).
// WIN covers bf16 quantization + accumulation-order + the +xsq rounding bin,
// so the np.argmin winner is always a candidate (same formula as r11/r12).
__global__ __launch_bounds__(256) void filter_kernel(
    const float* __restrict__ x, const short* __restrict__ Wbf,
    const float* __restrict__ wsq, const unsigned* __restrict__ maxwsq,
    float* __restrict__ xsq_g, int* __restrict__ cnt, int* __restrict__ cand) {
  __shared__ float xs[32][LPX];
  __shared__ float xsqs[32];
  __shared__ float umin_sh[32][4];
  const int tid = threadIdx.x;
  const int blkrow = blockIdx.x * 32;
  const int b = blockIdx.x >> 5, t0 = (blockIdx.x & 31) << 5;

  {  // stage x rows (coalesced along t)
    int tt = tid & 31, d0 = (tid >> 5) * 16;
    for (int dd = 0; dd < 16; ++dd) {
      int d = d0 + dd;
      xs[tt][d] = x[((size_t)b * D_ + d) * T_ + t0 + tt];
    }
  }
  __syncthreads();
  if (tid < 32) {
    float s = np_sumsq128(&xs[tid][0]);
    xsqs[tid] = s;
    xsq_g[blkrow + tid] = s;
  }
  __syncthreads();

  const int w = tid >> 6, lane = tid & 63;
  const int cidx = lane & 15;         // code within ct tile
  const int q = lane >> 4;            // k-slice / C-row group

  // A fragments for both row-tiles: lane holds row t*16+(lane&15), k = kk*32+q*8+j
  short8 afr0[4], afr1[4];
#pragma unroll
  for (int kk = 0; kk < 4; ++kk)
#pragma unroll
    for (int j = 0; j < 8; ++j) {
      int k = (kk << 5) + (q << 3) + j;
      afr0[kk][j] = bf16_rne(xs[cidx][k]);
      afr1[kk][j] = bf16_rne(xs[16 + cidx][k]);
    }

  const float mw = sqrtf(__uint_as_float(*maxwsq)) * 1.0001f;

  float umin[2][4] = {{INF_, INF_, INF_, INF_}, {INF_, INF_, INF_, INF_}};
  float lim[2][4] = {{INF_, INF_, INF_, INF_}, {INF_, INF_, INF_, INF_}};
  const int ct0 = w << 6;             // this wave's 64-ct quarter

  for (int phase = 0; phase < 2; ++phase) {
    const char*  pwb = (const char*)Wbf + (size_t)ct0 * 4096 + (size_t)lane * 16;
    const float* pwq = wsq + (ct0 << 4) + cidx;
    short8 p0, p1, p2, p3, n0, n1, n2, n3;
    float wqc, wqn;
    LDB(p0, p1, p2, p3, wqc)          // ct0
    for (int s = 0; s < 32; ++s) {
      const int c = ct0 + s * 2;
      LDB(n0, n1, n2, n3, wqn)        // ct0+2s+1
      SCHED_FENCE();
      CONSUME(p0, p1, p2, p3, wqc, c);
      SCHED_FENCE();
      LDB(p0, p1, p2, p3, wqc)        // ct0+2s+2 (last iter overreads mapped slack)
      SCHED_FENCE();
      CONSUME(n0, n1, n2, n3, wqn, c + 1);
      SCHED_FENCE();
    }
    if (phase == 0) {
      // min over the 16 code-lanes (butterfly) -> per-row quarter-min
#pragma unroll
      for (int t = 0; t < 2; ++t)
#pragma unroll
        for (int j = 0; j < 4; ++j) {
          float m = umin[t][j];
#pragma unroll
          for (int mask = 1; mask < 16; mask <<= 1)
            m = fminf(m, __shfl_xor(m, mask));
          if (cidx == 0) umin_sh[t * 16 + (q << 2) + j][w] = m;
        }
      __syncthreads();
      // merge quarters + window
#pragma unroll
      for (int t = 0; t < 2; ++t)
#pragma unroll
        for (int j = 0; j < 4; ++j) {
          int rl = t * 16 + (q << 2) + j;
          float m2 = fminf(fminf(umin_sh[rl][0], umin_sh[rl][1]),
                           fminf(umin_sh[rl][2], umin_sh[rl][3]));
          float xn = sqrtf(xsqs[rl]) * 1.0001f;
          lim[t][j] = m2 + 4.f * (0.0079f * xn * mw + 1e-5f) + 2.6e-5f;
        }
    }
  }
}

// Exact rescore: lane c replays the bit-exact np fp32 pipeline for candidate c;
// lexicographic (v, k) min == np.argmin first-occurrence.
__global__ __launch_bounds__(256) void rescore_kernel(
    const float* __restrict__ x, const float* __restrict__ W,
    const float* __restrict__ wsq, const float* __restrict__ xsq,
    const int* __restrict__ cnt, const int* __restrict__ cand,
    int* __restrict__ qout, float* __restrict__ out2) {
  const int wid = threadIdx.x >> 6, lane = threadIdx.x & 63;
  const int r = blockIdx.x * 4 + wid;
  int c = cnt[r]; if (c > 16) c = 16;
  int best;
  if (c == 1) {
    best = cand[r << 4] & (K_ - 1);
  } else {
    float v = INF_; int k = 0x7fffffff;
    if (lane < c) {
      k = cand[(r << 4) + lane] & (K_ - 1);
      const float* wr = W + (size_t)k * D_;
      const float* xr = x + ((size_t)(r >> 10) * D_) * T_ + (r & 1023);
      float mm = 0.f;
#pragma unroll 16
      for (int d = 0; d < D_; ++d)
        mm = __fmaf_rn(xr[(size_t)d * T_], wr[d], mm);   // ascending-d sgemm chain
      v = __fadd_rn(__fmaf_rn(-2.f, mm, wsq[k]), xsq[r]);  // RN(wq-2mm) then +xsq
    }
#pragma unroll
    for (int mask = 1; mask < 16; mask <<= 1) {
      float vo = __shfl_xor(v, mask); int ko = __shfl_xor(k, mask);
      if (vo < v || (vo == v && ko < k)) { v = vo; k = ko; }
    }
    best = k & (K_ - 1);   // clamp: wrong-but-deterministic if cnt==0, never OOB
  }
  if (lane == 0) { qout[r] = best; out2[r] = (float)best; }
}

// out0[r, d] = W[q[r], d]  — coalesced along d
__global__ void scatter0_kernel(const float* __restrict__ W,
                                const int* __restrict__ q,
                                float* __restrict__ out0) {
  int r = blockIdx.x * 2 + (threadIdx.x >> 7);
  int d = threadIdx.x & 127;
  int k = q[r] & (K_ - 1);
  out0[(size_t)r * D_ + d] = W[(size_t)k * D_ + d];
}

// out1[b, d, t] = W[q[b,t], d]  — coalesced along t
__global__ void scatter1_kernel(const float* __restrict__ W,
                                const int* __restrict__ q,
                                float* __restrict__ out1) {
  int b = blockIdx.x >> 7;
  int d = blockIdx.x & 127;
  for (int t = threadIdx.x; t < T_; t += 256) {
    int k = q[b * T_ + t] & (K_ - 1);
    out1[((size_t)b * D_ + d) * T_ + t] = W[(size_t)k * D_ + d];
  }
}

extern "C" void kernel_launch(void* const* d_in, const int* in_sizes, int n_in,
                              void* d_out, int out_size, void* d_ws, size_t ws_size,
                              hipStream_t stream) {
  const float* x = (const float*)d_in[0];
  const float* W = (const float*)d_in[1];
  float* out  = (float*)d_out;
  float* out0 = out;                           // [B,T,D]  4194304
  float* out1 = out + (size_t)NROWS * D_;      // [B,D,T]  4194304
  float* out2 = out + 2 * (size_t)NROWS * D_;  // [B,T]    32768 (as float)

  // small scratch in ws (~404 KB; r9/r10 proved >=656 KB usable)
  float*    wsq  = (float*)d_ws;                               // 16 KB
  float*    xsq  = (float*)((char*)d_ws + (16 << 10));         // 128 KB
  int*      q    = (int*)((char*)d_ws + (144 << 10));          // 128 KB
  int*      cnt  = (int*)((char*)d_ws + (272 << 10));          // 128 KB
  unsigned* maxw = (unsigned*)((char*)d_ws + (400 << 10));     // 4 B

  // big scratch in out0 (read before scatter0 overwrites it; stream-ordered)
  int*   cand = (int*)out0;                          // 32768*16*4 = 2 MB
  short* Wbf  = (short*)((char*)(void*)out0 + (2 << 20));  // 1 MB

  hipMemsetAsync((char*)d_ws + (272 << 10), 0, (128 << 10) + 64, stream);  // cnt + maxw
  wsq_kernel<<<K_ / 256, 256, 0, stream>>>(W, wsq, maxw);
  wbf_prep_kernel<<<K_ * D_ / 256, 256, 0, stream>>>(W, Wbf);
  filter_kernel<<<NROWS / 32, 256, 0, stream>>>(x, Wbf, wsq, maxw, xsq, cnt, cand);
  rescore_kernel<<<NROWS / 4, 256, 0, stream>>>(x, W, wsq, xsq, cnt, cand, q, out2);
  scatter0_kernel<<<NROWS / 2, 256, 0, stream>>>(W, q, out0);
  scatter1_kernel<<<B_ * D_, 256, 0, stream>>>(W, q, out1);
}